// Round 16
// baseline (230.667 us; speedup 1.0000x reference)
//
#include <hip/hip_runtime.h>
#include <math.h>

#define SEQ   2048
#define HD    128
#define KVB   64
#define NT    (SEQ / KVB)
// (1/sqrt(128)) * log2(e)
#define SCALE_L2E 0.12753242193263556f

typedef __bf16 bf16_t;
typedef __bf16 bf16x2 __attribute__((ext_vector_type(2)));
typedef __bf16 bf16x4 __attribute__((ext_vector_type(4)));
typedef __bf16 bf16x8 __attribute__((ext_vector_type(8)));
typedef float  f32x16 __attribute__((ext_vector_type(16)));

// direct global->LDS DMA, 16B per lane (global addr per-lane, LDS base wave-uniform)
__device__ __forceinline__ void gl_lds16(const void* g, void* l) {
  __builtin_amdgcn_global_load_lds(
      (const __attribute__((address_space(1))) unsigned int*)g,
      (__attribute__((address_space(3))) unsigned int*)l, 16, 0, 0);
}

// ---------------------------------------------------------------------------
// Prepass 1: K LDS-image. img[(r*256 + c*2) ^ ((r&7)<<4)] = bf16(K[t*64+r][c])
// ---------------------------------------------------------------------------
__global__ __launch_bounds__(256)
void mk_kimg(const float* __restrict__ k, char* __restrict__ img) {
  const int bt = blockIdx.x;                       // bh*NT + t
  const float* src = k + (size_t)bt * KVB * HD;
  char* dst = img + (size_t)bt * 16384;
  const int tid = threadIdx.x;
#pragma unroll
  for (int i = 0; i < 8; ++i) {
    const int g = tid + i * 256;
    const int r = g >> 5, c4 = g & 31;
    float4 v = *(const float4*)(src + (size_t)r * HD + c4 * 4);
    const int o = (r * 256 + c4 * 8) ^ ((r & 7) << 4);
    *(bf16x4*)(dst + o) = bf16x4{(bf16_t)v.x, (bf16_t)v.y, (bf16_t)v.z, (bf16_t)v.w};
  }
}

// ---------------------------------------------------------------------------
// Prepass 2: V^T LDS-image (phys-k permutation baked in; see R12 derivation)
// ---------------------------------------------------------------------------
__global__ __launch_bounds__(256)
void mk_vimg(const float* __restrict__ v, char* __restrict__ img) {
  __shared__ float tile[KVB][HD + 4];
  const int bt = blockIdx.x;
  const float* src = v + (size_t)bt * KVB * HD;
  char* dst = img + (size_t)bt * 16384;
  const int tid = threadIdx.x;
#pragma unroll
  for (int i = 0; i < 8; ++i) {
    const int g = tid + i * 256;
    const int r = g >> 5, c4 = g & 31;
    float4 a = *(const float4*)(src + (size_t)r * HD + c4 * 4);
    tile[r][c4 * 4 + 0] = a.x; tile[r][c4 * 4 + 1] = a.y;
    tile[r][c4 * 4 + 2] = a.z; tile[r][c4 * 4 + 3] = a.w;
  }
  __syncthreads();
#pragma unroll
  for (int i = 0; i < 8; ++i) {
    const int g = tid + i * 256;          // 8B image chunk index
    const int o = g * 8;
    const int d = o >> 7;
    const int inner = (o & 127) ^ ((d & 7) << 4);
    const int pe0 = inner >> 1;
    bf16x4 w;
#pragma unroll
    for (int e = 0; e < 4; ++e) {
      const int pe = pe0 + e;
      const int a  = pe >> 4;
      const int bp = pe & 15;
      const int vv = bp >> 1;
      const int sv = (vv & 1) | ((vv & 2) << 1) | ((vv & 4) >> 1);   // sw3
      const int kk = a * 16 + sv * 2 + (bp & 1);
      w[e] = (bf16_t)tile[kk][d];
    }
    *(bf16x4*)(dst + o) = w;
  }
}

// ---------------------------------------------------------------------------
// Prepass 3: MT2[(k>>6)*32 + (k&31)][q] = bf16x2( M[q][k]*s , M[q][k+32]*s )
// ---------------------------------------------------------------------------
__global__ __launch_bounds__(256)
void mask_tr2(const float* __restrict__ m, bf16x2* __restrict__ mt2) {
  __shared__ float tile[32][65];
  const int tid = threadIdx.x;
  const int k0  = blockIdx.x * 64;
  const int q0  = blockIdx.y * 32;
#pragma unroll
  for (int i = 0; i < 2; ++i) {
    const int ix = tid + i * 256;
    const int qr = ix >> 4, c4 = ix & 15;
    float4 v = *(const float4*)(m + (size_t)(q0 + qr) * SEQ + k0 + c4 * 4);
    tile[qr][c4 * 4 + 0] = v.x; tile[qr][c4 * 4 + 1] = v.y;
    tile[qr][c4 * 4 + 2] = v.z; tile[qr][c4 * 4 + 3] = v.w;
  }
  __syncthreads();
#pragma unroll
  for (int i = 0; i < 4; ++i) {
    const int ix = tid + i * 256;
    const int kl = ix >> 5, qq = ix & 31;
    mt2[(size_t)(blockIdx.x * 32 + kl) * SEQ + q0 + qq] =
        bf16x2{(bf16_t)(tile[qq][kl] * SCALE_L2E),
               (bf16_t)(tile[qq][kl + 32] * SCALE_L2E)};
  }
}

// ---------------------------------------------------------------------------
// Prepass 4 (fallback path): MT[k][q] = M[q][k] * SCALE_L2E (fp32)
// ---------------------------------------------------------------------------
__global__ __launch_bounds__(256)
void mask_tr(const float* __restrict__ m, float* __restrict__ mt) {
  __shared__ float tile[32][33];
  const int tx = threadIdx.x & 31;
  const int ty = threadIdx.x >> 5;
  const int kb = blockIdx.x * 32;
  const int qb = blockIdx.y * 32;
#pragma unroll
  for (int r = 0; r < 32; r += 8)
    tile[ty + r][tx] = m[(size_t)(qb + ty + r) * SEQ + kb + tx] * SCALE_L2E;
  __syncthreads();
#pragma unroll
  for (int r = 0; r < 32; r += 8)
    mt[(size_t)(kb + ty + r) * SEQ + qb + tx] = tile[tx][ty + r];
}

// ---------------------------------------------------------------------------
// Main v7: v6 (DMA images, no max-tracking, deferred l) restructured into a
// two-stream pipeline: per iteration  softmax(t) -> barrier -> [QK(t+1) || PV(t)]
// — 6 independent MFMA chains in the compute phase instead of a serial
// QK->softmax->PV chain. K double-buffered, V TRIPLE-buffered (PV(t) reads
// t%3 while STAGE V(t+2) fills (t+2)%3). 80 KiB LDS -> 2 blocks/CU = 160 KiB
// exactly. One barrier/iter. No setprio.
// ---------------------------------------------------------------------------
__global__ __launch_bounds__(256, 2)
void attn_fwd_v7(const float* __restrict__ q_g, const char* __restrict__ kimg,
                 const char* __restrict__ vimg, const bf16x2* __restrict__ mt2_g,
                 float* __restrict__ o_g) {
  __shared__ __align__(16) char ldsK[2][16384];
  __shared__ __align__(16) char ldsV[3][16384];

  const int tid  = threadIdx.x;
  const int wid  = tid >> 6;
  const int lane = tid & 63;
  const int hi   = lane >> 5;
  const int ql   = lane & 31;

  // XCD swizzle: keep each bh's q-blocks on one XCD (K/V image L2 residency)
  const int lin = blockIdx.x;           // 0..1023
  const int xcd = lin & 7;
  const int idx = lin >> 3;             // 0..127
  const int bh  = xcd + 8 * (idx >> 4); // 0..63
  const int q0  = (idx & 15) * 128;

  const float* Qb = q_g + (size_t)bh * SEQ * HD;
  float*       Ob = o_g + (size_t)bh * SEQ * HD;

  const int qrow = q0 + wid * 32 + ql;

  // ---- Q fragments (B-operand of QK): qf[kd] = Q[qrow][kd*16 + hi*8 + j] ----
  bf16x8 qf[8];
#pragma unroll
  for (int kd = 0; kd < 8; ++kd) {
    const float* p = Qb + (size_t)qrow * HD + kd * 16 + hi * 8;
    float4 a = *(const float4*)p;
    float4 b = *(const float4*)(p + 4);
    qf[kd] = bf16x8{(bf16_t)a.x, (bf16_t)a.y, (bf16_t)a.z, (bf16_t)a.w,
                    (bf16_t)b.x, (bf16_t)b.y, (bf16_t)b.z, (bf16_t)b.w};
  }

  f32x16 ot[4];
#pragma unroll
  for (int dt = 0; dt < 4; ++dt)
#pragma unroll
    for (int r = 0; r < 16; ++r) ot[dt][r] = 0.f;

  f32x16 lsum;
#pragma unroll
  for (int r = 0; r < 16; ++r) lsum[r] = 0.f;

#define STAGE_K(T, BUF)                                                      \
  { const char* gK = kimg + ((size_t)bh * NT + (T)) * 16384 + wid * 4096 +   \
                     lane * 16;                                              \
    char* lK = ldsK[BUF] + wid * 4096;                                       \
    _Pragma("unroll") for (int j = 0; j < 4; ++j)                            \
      gl_lds16(gK + j * 1024, lK + j * 1024); }

#define STAGE_V(T, BUF)                                                      \
  { const char* gV = vimg + ((size_t)bh * NT + (T)) * 16384 + wid * 4096 +   \
                     lane * 16;                                              \
    char* lV = ldsV[BUF] + wid * 4096;                                       \
    _Pragma("unroll") for (int j = 0; j < 4; ++j)                            \
      gl_lds16(gV + j * 1024, lV + j * 1024); }

#define LOAD_MASK(T)                                                         \
  { const bf16x2* MTp = mt2_g + (size_t)((T) * 32) * SEQ + qrow;             \
    _Pragma("unroll") for (int r = 0; r < 16; ++r) {                         \
      const int kl = (r & 3) + 8 * (r >> 2) + 4 * hi;                        \
      mcur[r] = MTp[(size_t)kl * SEQ]; } }

  bf16x2 mcur[16];

  // ---- prologue ----
  STAGE_K(0, 0)
  STAGE_V(0, 0)
  LOAD_MASK(0)
  __syncthreads();                       // tile 0 + mask(0) landed
  STAGE_K(1, 1)                          // flies under QK(0)
  STAGE_V(1, 1)

  f32x16 s0, s1;
#pragma unroll
  for (int r = 0; r < 16; ++r) { s0[r] = 0.f; s1[r] = 0.f; }
  {
    const char* Kl = ldsK[0];
#pragma unroll
    for (int kd = 0; kd < 8; ++kd) {
      int b0 = ql * 256 + kd * 32 + hi * 16; b0 ^= (ql & 7) << 4;
      bf16x8 kf0 = *(const bf16x8*)(Kl + b0);
      bf16x8 kf1 = *(const bf16x8*)(Kl + b0 + 8192);
      s0 = __builtin_amdgcn_mfma_f32_32x32x16_bf16(kf0, qf[kd], s0, 0, 0, 0);
      s1 = __builtin_amdgcn_mfma_f32_32x32x16_bf16(kf1, qf[kd], s1, 0, 0, 0);
    }
  }

  for (int t = 0; t < NT; ++t) {
    // ---- softmax(t): s -> p -> pb (VALU only, no cross-lane) ----
    float p0[16], p1[16];
#pragma unroll
    for (int r = 0; r < 16; ++r) {
      p0[r] = __builtin_amdgcn_exp2f(fmaf(s0[r], SCALE_L2E, (float)mcur[r][0]));
      p1[r] = __builtin_amdgcn_exp2f(fmaf(s1[r], SCALE_L2E, (float)mcur[r][1]));
    }
#pragma unroll
    for (int r = 0; r < 16; ++r) lsum[r] += p0[r] + p1[r];

    bf16x8 pb[2][2];
#pragma unroll
    for (int kf = 0; kf < 2; ++kf) {
      pb[0][kf] = bf16x8{(bf16_t)p0[8*kf+0], (bf16_t)p0[8*kf+1],
                         (bf16_t)p0[8*kf+2], (bf16_t)p0[8*kf+3],
                         (bf16_t)p0[8*kf+4], (bf16_t)p0[8*kf+5],
                         (bf16_t)p0[8*kf+6], (bf16_t)p0[8*kf+7]};
      pb[1][kf] = bf16x8{(bf16_t)p1[8*kf+0], (bf16_t)p1[8*kf+1],
                         (bf16_t)p1[8*kf+2], (bf16_t)p1[8*kf+3],
                         (bf16_t)p1[8*kf+4], (bf16_t)p1[8*kf+5],
                         (bf16_t)p1[8*kf+6], (bf16_t)p1[8*kf+7]};
    }

    if (t + 1 < NT) { LOAD_MASK(t + 1) }   // drains at next softmax

    __syncthreads();   // K(t+1),V(t+1) DMA landed; all QK(t)/PV(t-1) reads done

    if (t + 2 < NT) {
      STAGE_K(t + 2, t & 1)          // K(t)'s buffer: QK(t) reads finished last iter
      STAGE_V(t + 2, (t + 2) % 3)    // V(t-1)'s buffer: PV(t-1) reads finished
    }

    // ---- compute phase: QK(t+1) || PV(t) — 6 independent MFMA chains ----
    const char* Vl = ldsV[t % 3];
    if (t + 1 < NT) {
      const char* Kl = ldsK[(t + 1) & 1];
#pragma unroll
      for (int r = 0; r < 16; ++r) { s0[r] = 0.f; s1[r] = 0.f; }
#pragma unroll
      for (int kd = 0; kd < 8; ++kd) {
        int b0 = ql * 256 + kd * 32 + hi * 16; b0 ^= (ql & 7) << 4;
        bf16x8 kf0 = *(const bf16x8*)(Kl + b0);
        bf16x8 kf1 = *(const bf16x8*)(Kl + b0 + 8192);
        s0 = __builtin_amdgcn_mfma_f32_32x32x16_bf16(kf0, qf[kd], s0, 0, 0, 0);
        s1 = __builtin_amdgcn_mfma_f32_32x32x16_bf16(kf1, qf[kd], s1, 0, 0, 0);
        // 2 PV MFMAs interleaved per kd step (16 total over 8 steps)
#pragma unroll
        for (int u = 0; u < 2; ++u) {
          const int i  = kd * 2 + u;
          const int tt = i >> 3, kf = (i >> 2) & 1, dt = i & 3;
          const int kg = tt * 2 + kf;
          const int d  = dt * 32 + ql;
          int byt = d * 128 + kg * 32 + hi * 16; byt ^= (d & 7) << 4;
          bf16x8 vf = *(const bf16x8*)(Vl + byt);
          ot[dt] = __builtin_amdgcn_mfma_f32_32x32x16_bf16(vf, pb[tt][kf], ot[dt], 0, 0, 0);
        }
      }
    } else {
      // last tile: PV only
#pragma unroll
      for (int i = 0; i < 16; ++i) {
        const int tt = i >> 3, kf = (i >> 2) & 1, dt = i & 3;
        const int kg = tt * 2 + kf;
        const int d  = dt * 32 + ql;
        int byt = d * 128 + kg * 32 + hi * 16; byt ^= (d & 7) << 4;
        bf16x8 vf = *(const bf16x8*)(Vl + byt);
        ot[dt] = __builtin_amdgcn_mfma_f32_32x32x16_bf16(vf, pb[tt][kf], ot[dt], 0, 0, 0);
      }
    }
  }

  // ---- epilogue: single l reduction, then O[q][d] = O^T / l ----
  float ls[16];
#pragma unroll
  for (int r = 0; r < 16; ++r) ls[r] = lsum[r];
#pragma unroll
  for (int off = 8; off > 0; off >>= 1)
#pragma unroll
    for (int r = 0; r < off; ++r) ls[r] += ls[r + off];
  const float l_run = ls[0] + __shfl_xor(ls[0], 32, 64);

  const float rinv = 1.f / l_run;
  float* Op = Ob + (size_t)qrow * HD;
#pragma unroll
  for (int dt = 0; dt < 4; ++dt)
#pragma unroll
    for (int r = 0; r < 16; ++r) {
      const int d = dt * 32 + (r & 3) + 8 * (r >> 2) + 4 * hi;
      Op[d] = ot[dt][r] * rinv;
    }
}

// ---------------------------------------------------------------------------
// Fallback: R4 champion (fp32 K/V staging, fp32 transposed mask)
// ---------------------------------------------------------------------------
__global__ __launch_bounds__(256, 2)
void attn_fwd_fb(const float* __restrict__ q_g, const float* __restrict__ k_g,
                 const float* __restrict__ v_g, const float* __restrict__ mt_g,
                 float* __restrict__ o_g) {
  __shared__ __align__(16) char ldsK[2][KVB * 256];
  __shared__ __align__(16) char ldsV[2][HD * 128];

  const int tid  = threadIdx.x;
  const int wid  = tid >> 6;
  const int lane = tid & 63;
  const int hi   = lane >> 5;
  const int ql   = lane & 31;

  const int lin = blockIdx.x;
  const int xcd = lin & 7;
  const int idx = lin >> 3;
  const int bh  = xcd + 8 * (idx >> 4);
  const int q0  = (idx & 15) * 128;

  const float* Qb = q_g + (size_t)bh * SEQ * HD;
  const float* Kb = k_g + (size_t)bh * SEQ * HD;
  const float* Vb = v_g + (size_t)bh * SEQ * HD;
  float*       Ob = o_g + (size_t)bh * SEQ * HD;

  const int qrow = q0 + wid * 32 + ql;

  bf16x8 qf[8];
#pragma unroll
  for (int kd = 0; kd < 8; ++kd) {
    const float* p = Qb + (size_t)qrow * HD + kd * 16 + hi * 8;
    float4 a = *(const float4*)p;
    float4 b = *(const float4*)(p + 4);
    qf[kd] = bf16x8{(bf16_t)a.x, (bf16_t)a.y, (bf16_t)a.z, (bf16_t)a.w,
                    (bf16_t)b.x, (bf16_t)b.y, (bf16_t)b.z, (bf16_t)b.w};
  }

  f32x16 ot[4];
#pragma unroll
  for (int dt = 0; dt < 4; ++dt)
#pragma unroll
    for (int r = 0; r < 16; ++r) ot[dt][r] = 0.f;

  float m_run = -INFINITY, l_run = 0.f;

  float4 kreg[8], vA[4], vB[4];
  const int vp  = tid & 31;
  const int vcb = tid >> 5;
  const int vkb = ((vp >> 3) << 5) +
                  (((vp & 1) | ((vp & 2) << 1) | ((vp & 4) >> 1)) << 2);

#define KF_ISSUE(K0)                                                         \
  { _Pragma("unroll") for (int i = 0; i < 8; ++i) {                          \
      const int ix = tid + i * 256;                                          \
      kreg[i] = *(const float4*)(Kb + (size_t)((K0) + (ix >> 5)) * HD +      \
                                 (ix & 31) * 4); } }

#define KF_WRITE(BUF)                                                        \
  { char* dK = ldsK[BUF];                                                    \
    _Pragma("unroll") for (int i = 0; i < 8; ++i) {                          \
      const int ix = tid + i * 256;                                          \
      const int row = ix >> 5; const int c4 = ix & 31;                       \
      int byt = row * 256 + c4 * 8; byt ^= (row & 7) << 4;                   \
      float4 v = kreg[i];                                                    \
      *(bf16x4*)(dK + byt) =                                                 \
          bf16x4{(bf16_t)v.x, (bf16_t)v.y, (bf16_t)v.z, (bf16_t)v.w}; } }

#define VF_ISSUE_A(K0)                                                       \
  { _Pragma("unroll") for (int i = 0; i < 2; ++i) {                          \
      const int c4 = vcb + 8 * i;                                            \
      vA[2*i]   = *(const float4*)(Vb + (size_t)((K0) + 2*vp)     * HD + c4*4); \
      vA[2*i+1] = *(const float4*)(Vb + (size_t)((K0) + 2*vp + 1) * HD + c4*4); } }

#define VF_ISSUE_B(K0)                                                       \
  { _Pragma("unroll") for (int i = 0; i < 2; ++i) {                          \
      const int c4 = vcb + 16 + 8 * i;                                       \
      vB[2*i]   = *(const float4*)(Vb + (size_t)((K0) + 2*vp)     * HD + c4*4); \
      vB[2*i+1] = *(const float4*)(Vb + (size_t)((K0) + 2*vp + 1) * HD + c4*4); } }

#define VF_WRITE_X(BUF, REGS, COFF)                                          \
  { char* dV = ldsV[BUF];                                                    \
    _Pragma("unroll") for (int i = 0; i < 2; ++i) {                          \
      const int c4 = vcb + (COFF) + 8 * i;                                   \
      const float* r0 = (const float*)&REGS[2*i];                            \
      const float* r1 = (const float*)&REGS[2*i+1];                          \
      _Pragma("unroll") for (int j = 0; j < 4; ++j) {                        \
        const int d = c4 * 4 + j;                                            \
        int byt = d * 128 + vkb; byt ^= (d & 7) << 4;                        \
        *(bf16x2*)(dV + byt) = bf16x2{(bf16_t)r0[j], (bf16_t)r1[j]}; } } }

  KF_ISSUE(0)
  VF_ISSUE_A(0)
  VF_ISSUE_B(0)
  KF_WRITE(0)
  VF_WRITE_X(0, vA, 0)
  VF_WRITE_X(0, vB, 16)

  for (int t = 0; t < NT; ++t) {
    __syncthreads();
    const int buf = t & 1;
    const char* Kl = ldsK[buf];
    const char* Vl = ldsV[buf];
    const bool more = (t + 1 < NT);

    if (more) { KF_ISSUE((t + 1) * KVB) }

    float mk0[16], mk1[16];
    {
      const float* MTp = mt_g + (size_t)(t * KVB) * SEQ + qrow;
#pragma unroll
      for (int r = 0; r < 16; ++r) {
        const int k = (r & 3) + 8 * (r >> 2) + 4 * hi;
        mk0[r] = MTp[(size_t)k * SEQ];
        mk1[r] = MTp[(size_t)(k + 32) * SEQ];
      }
    }

    if (more) { VF_ISSUE_A((t + 1) * KVB) }

    f32x16 s0, s1;
#pragma unroll
    for (int r = 0; r < 16; ++r) { s0[r] = 0.f; s1[r] = 0.f; }
#pragma unroll
    for (int kd = 0; kd < 8; ++kd) {
      int b0 = ql * 256 + kd * 32 + hi * 16; b0 ^= (ql & 7) << 4;
      bf16x8 kf0 = *(const bf16x8*)(Kl + b0);
      bf16x8 kf1 = *(const bf16x8*)(Kl + b0 + 8192);
      s0 = __builtin_amdgcn_mfma_f32_32x32x16_bf16(kf0, qf[kd], s0, 0, 0, 0);
      s1 = __builtin_amdgcn_mfma_f32_32x32x16_bf16(kf1, qf[kd], s1, 0, 0, 0);
    }

    if (more) {
      VF_WRITE_X(buf ^ 1, vA, 0)
      VF_ISSUE_B((t + 1) * KVB)
    }

    float x0[16], x1[16];
#pragma unroll
    for (int r = 0; r < 16; ++r) {
      x0[r] = fmaf(s0[r], SCALE_L2E, mk0[r]);
      x1[r] = fmaf(s1[r], SCALE_L2E, mk1[r]);
    }
    float tm[16];
#pragma unroll
    for (int r = 0; r < 16; ++r) tm[r] = fmaxf(x0[r], x1[r]);
#pragma unroll
    for (int off = 8; off > 0; off >>= 1)
#pragma unroll
      for (int r = 0; r < off; ++r) tm[r] = fmaxf(tm[r], tm[r + off]);
    const float mx   = fmaxf(tm[0], __shfl_xor(tm[0], 32, 64));
    const float mnew = fmaxf(m_run, mx);
    const float fac  = __builtin_amdgcn_exp2f(m_run - mnew);
    m_run = mnew;

    float p0[16], p1[16];
#pragma unroll
    for (int r = 0; r < 16; ++r) {
      p0[r] = __builtin_amdgcn_exp2f(x0[r] - mnew);
      p1[r] = __builtin_amdgcn_exp2f(x1[r] - mnew);
    }
    float ts[16];
#pragma unroll
    for (int r = 0; r < 16; ++r) ts[r] = p0[r] + p1[r];
#pragma unroll
    for (int off = 8; off > 0; off >>= 1)
#pragma unroll
      for (int r = 0; r < off; ++r) ts[r] += ts[r + off];
    const float sum = ts[0] + __shfl_xor(ts[0], 32, 64);
    l_run = l_run * fac + sum;

#pragma unroll
    for (int dt = 0; dt < 4; ++dt)
#pragma unroll
      for (int r = 0; r < 16; ++r) ot[dt][r] *= fac;

    bf16x8 pb[2][2];
#pragma unroll
    for (int kf = 0; kf < 2; ++kf) {
      pb[0][kf] = bf16x8{(bf16_t)p0[8*kf+0], (bf16_t)p0[8*kf+1],
                         (bf16_t)p0[8*kf+2], (bf16_t)p0[8*kf+3],
                         (bf16_t)p0[8*kf+4], (bf16_t)p0[8*kf+5],
                         (bf16_t)p0[8*kf+6], (bf16_t)p0[8*kf+7]};
      pb[1][kf] = bf16x8{(bf16_t)p1[8*kf+0], (bf16_t)p1[8*kf+1],
                         (bf16_t)p1[8*kf+2], (bf16_t)p1[8*kf+3],
                         (bf16_t)p1[8*kf+4], (bf16_t)p1[8*kf+5],
                         (bf16_t)p1[8*kf+6], (bf16_t)p1[8*kf+7]};
    }

#pragma unroll
    for (int tt = 0; tt < 2; ++tt)
#pragma unroll
      for (int kf = 0; kf < 2; ++kf) {
        const int kg = tt * 2 + kf;
#pragma unroll
        for (int dt = 0; dt < 4; ++dt) {
          const int d = dt * 32 + ql;
          int byt = d * 128 + kg * 32 + hi * 16; byt ^= (d & 7) << 4;
          bf16x8 vf = *(const bf16x8*)(Vl + byt);
          ot[dt] = __builtin_amdgcn_mfma_f32_32x32x16_bf16(vf, pb[tt][kf], ot[dt], 0, 0, 0);
        }
      }

    if (more) {
      VF_WRITE_X(buf ^ 1, vB, 16)
      KF_WRITE(buf ^ 1)
    }
  }

  const float rinv = 1.f / l_run;
  float* Op = Ob + (size_t)qrow * HD;
#pragma unroll
  for (int dt = 0; dt < 4; ++dt)
#pragma unroll
    for (int r = 0; r < 16; ++r) {
      const int d = dt * 32 + (r & 3) + 8 * (r >> 2) + 4 * hi;
      Op[d] = ot[dt][r] * rinv;
    }
}

extern "C" void kernel_launch(void* const* d_in, const int* in_sizes, int n_in,
                              void* d_out, int out_size, void* d_ws, size_t ws_size,
                              hipStream_t stream) {
  (void)in_sizes; (void)n_in; (void)out_size;
  const float* Q = (const float*)d_in[0];
  const float* K = (const float*)d_in[1];
  const float* V = (const float*)d_in[2];
  const float* M = (const float*)d_in[3];
  float*       O = (float*)d_out;

  const size_t szImg = (size_t)64 * NT * 16384;            // 33.55 MB per image
  const size_t szM2  = (size_t)(SEQ / KVB) * 32 * SEQ * 4; // 8.39 MB

  if (ws_size >= 2 * szImg + szM2) {
    char*   KI  = (char*)d_ws;
    char*   VI  = (char*)d_ws + szImg;
    bf16x2* MT2 = (bf16x2*)((char*)d_ws + 2 * szImg);
    mk_kimg<<<64 * NT, 256, 0, stream>>>(K, KI);
    mk_vimg<<<64 * NT, 256, 0, stream>>>(V, VI);
    mask_tr2<<<dim3(SEQ / 64, SEQ / 32), 256, 0, stream>>>(M, MT2);
    attn_fwd_v7<<<dim3(1024), 256, 0, stream>>>(Q, KI, VI, MT2, O);
  } else {
    float* MT = (float*)d_ws;   // 16.8 MB (proven available)
    mask_tr<<<dim3(SEQ / 32, SEQ / 32), 256, 0, stream>>>(M, MT);
    attn_fwd_fb<<<dim3(1024), 256, 0, stream>>>(Q, K, V, MT, O);
  }
}

// Round 17
// 214.428 us; speedup vs baseline: 1.0757x; 1.0757x over previous
//
#include <hip/hip_runtime.h>
#include <math.h>

#define SEQ   2048
#define HD    128
#define KVB   64
#define NT    (SEQ / KVB)
// (1/sqrt(128)) * log2(e)
#define SCALE_L2E 0.12753242193263556f

typedef __bf16 bf16_t;
typedef __bf16 bf16x2 __attribute__((ext_vector_type(2)));
typedef __bf16 bf16x4 __attribute__((ext_vector_type(4)));
typedef __bf16 bf16x8 __attribute__((ext_vector_type(8)));
typedef float  f32x16 __attribute__((ext_vector_type(16)));

// direct global->LDS DMA, 16B per lane (global addr per-lane, LDS base wave-uniform)
__device__ __forceinline__ void gl_lds16(const void* g, void* l) {
  __builtin_amdgcn_global_load_lds(
      (const __attribute__((address_space(1))) unsigned int*)g,
      (__attribute__((address_space(3))) unsigned int*)l, 16, 0, 0);
}

// ---------------------------------------------------------------------------
// Prepass 1: K LDS-image. img[(r*256 + c*2) ^ ((r&7)<<4)] = bf16(K[t*64+r][c])
// ---------------------------------------------------------------------------
__global__ __launch_bounds__(256)
void mk_kimg(const float* __restrict__ k, char* __restrict__ img) {
  const int bt = blockIdx.x;                       // bh*NT + t
  const float* src = k + (size_t)bt * KVB * HD;
  char* dst = img + (size_t)bt * 16384;
  const int tid = threadIdx.x;
#pragma unroll
  for (int i = 0; i < 8; ++i) {
    const int g = tid + i * 256;
    const int r = g >> 5, c4 = g & 31;
    float4 v = *(const float4*)(src + (size_t)r * HD + c4 * 4);
    const int o = (r * 256 + c4 * 8) ^ ((r & 7) << 4);
    *(bf16x4*)(dst + o) = bf16x4{(bf16_t)v.x, (bf16_t)v.y, (bf16_t)v.z, (bf16_t)v.w};
  }
}

// ---------------------------------------------------------------------------
// Prepass 2: V^T LDS-image (phys-k permutation baked in; see R12 derivation)
// ---------------------------------------------------------------------------
__global__ __launch_bounds__(256)
void mk_vimg(const float* __restrict__ v, char* __restrict__ img) {
  __shared__ float tile[KVB][HD + 4];
  const int bt = blockIdx.x;
  const float* src = v + (size_t)bt * KVB * HD;
  char* dst = img + (size_t)bt * 16384;
  const int tid = threadIdx.x;
#pragma unroll
  for (int i = 0; i < 8; ++i) {
    const int g = tid + i * 256;
    const int r = g >> 5, c4 = g & 31;
    float4 a = *(const float4*)(src + (size_t)r * HD + c4 * 4);
    tile[r][c4 * 4 + 0] = a.x; tile[r][c4 * 4 + 1] = a.y;
    tile[r][c4 * 4 + 2] = a.z; tile[r][c4 * 4 + 3] = a.w;
  }
  __syncthreads();
#pragma unroll
  for (int i = 0; i < 8; ++i) {
    const int g = tid + i * 256;          // 8B image chunk index
    const int o = g * 8;
    const int d = o >> 7;
    const int inner = (o & 127) ^ ((d & 7) << 4);
    const int pe0 = inner >> 1;
    bf16x4 w;
#pragma unroll
    for (int e = 0; e < 4; ++e) {
      const int pe = pe0 + e;
      const int a  = pe >> 4;
      const int bp = pe & 15;
      const int vv = bp >> 1;
      const int sv = (vv & 1) | ((vv & 2) << 1) | ((vv & 4) >> 1);   // sw3
      const int kk = a * 16 + sv * 2 + (bp & 1);
      w[e] = (bf16_t)tile[kk][d];
    }
    *(bf16x4*)(dst + o) = w;
  }
}

// ---------------------------------------------------------------------------
// Prepass 3: MT2[(k>>6)*32 + (k&31)][q] = bf16x2( M[q][k]*s , M[q][k+32]*s )
// ---------------------------------------------------------------------------
__global__ __launch_bounds__(256)
void mask_tr2(const float* __restrict__ m, bf16x2* __restrict__ mt2) {
  __shared__ float tile[32][65];
  const int tid = threadIdx.x;
  const int k0  = blockIdx.x * 64;
  const int q0  = blockIdx.y * 32;
#pragma unroll
  for (int i = 0; i < 2; ++i) {
    const int ix = tid + i * 256;
    const int qr = ix >> 4, c4 = ix & 15;
    float4 v = *(const float4*)(m + (size_t)(q0 + qr) * SEQ + k0 + c4 * 4);
    tile[qr][c4 * 4 + 0] = v.x; tile[qr][c4 * 4 + 1] = v.y;
    tile[qr][c4 * 4 + 2] = v.z; tile[qr][c4 * 4 + 3] = v.w;
  }
  __syncthreads();
#pragma unroll
  for (int i = 0; i < 4; ++i) {
    const int ix = tid + i * 256;
    const int kl = ix >> 5, qq = ix & 31;
    mt2[(size_t)(blockIdx.x * 32 + kl) * SEQ + q0 + qq] =
        bf16x2{(bf16_t)(tile[qq][kl] * SCALE_L2E),
               (bf16_t)(tile[qq][kl + 32] * SCALE_L2E)};
  }
}

// ---------------------------------------------------------------------------
// Prepass 4 (fallback path): MT[k][q] = M[q][k] * SCALE_L2E (fp32)
// ---------------------------------------------------------------------------
__global__ __launch_bounds__(256)
void mask_tr(const float* __restrict__ m, float* __restrict__ mt) {
  __shared__ float tile[32][33];
  const int tx = threadIdx.x & 31;
  const int ty = threadIdx.x >> 5;
  const int kb = blockIdx.x * 32;
  const int qb = blockIdx.y * 32;
#pragma unroll
  for (int r = 0; r < 32; r += 8)
    tile[ty + r][tx] = m[(size_t)(qb + ty + r) * SEQ + kb + tx] * SCALE_L2E;
  __syncthreads();
#pragma unroll
  for (int r = 0; r < 32; r += 8)
    mt[(size_t)(kb + ty + r) * SEQ + qb + tx] = tile[tx][ty + r];
}

// ---------------------------------------------------------------------------
// Main v8: v6's lean pipeline (DMA from pre-swizzled images, no max-tracking,
// deferred l-reduction, no cross-lane ops in the loop, no setprio) with K AND
// V double-buffered -> ONE barrier per iteration (v6 needed a second barrier
// only because K was single-buffered). DMA for t+1 issues right after the
// mask loads and ages across the entire compute phase; softmax's mask wait
// (vmcnt to mask depth) leaves the younger DMAs in flight.
// ---------------------------------------------------------------------------
__global__ __launch_bounds__(256, 2)
void attn_fwd_v8(const float* __restrict__ q_g, const char* __restrict__ kimg,
                 const char* __restrict__ vimg, const bf16x2* __restrict__ mt2_g,
                 float* __restrict__ o_g) {
  __shared__ __align__(16) char ldsK[2][16384];
  __shared__ __align__(16) char ldsV[2][16384];

  const int tid  = threadIdx.x;
  const int wid  = tid >> 6;
  const int lane = tid & 63;
  const int hi   = lane >> 5;
  const int ql   = lane & 31;

  // XCD swizzle: keep each bh's q-blocks on one XCD (K/V image L2 residency)
  const int lin = blockIdx.x;           // 0..1023
  const int xcd = lin & 7;
  const int idx = lin >> 3;             // 0..127
  const int bh  = xcd + 8 * (idx >> 4); // 0..63
  const int q0  = (idx & 15) * 128;

  const float* Qb = q_g + (size_t)bh * SEQ * HD;
  float*       Ob = o_g + (size_t)bh * SEQ * HD;

  const int qrow = q0 + wid * 32 + ql;

  // ---- Q fragments (B-operand of QK): qf[kd] = Q[qrow][kd*16 + hi*8 + j] ----
  bf16x8 qf[8];
#pragma unroll
  for (int kd = 0; kd < 8; ++kd) {
    const float* p = Qb + (size_t)qrow * HD + kd * 16 + hi * 8;
    float4 a = *(const float4*)p;
    float4 b = *(const float4*)(p + 4);
    qf[kd] = bf16x8{(bf16_t)a.x, (bf16_t)a.y, (bf16_t)a.z, (bf16_t)a.w,
                    (bf16_t)b.x, (bf16_t)b.y, (bf16_t)b.z, (bf16_t)b.w};
  }

  f32x16 ot[4];
#pragma unroll
  for (int dt = 0; dt < 4; ++dt)
#pragma unroll
    for (int r = 0; r < 16; ++r) ot[dt][r] = 0.f;

  f32x16 lsum;
#pragma unroll
  for (int r = 0; r < 16; ++r) lsum[r] = 0.f;

#define STAGE_K(T, BUF)                                                      \
  { const char* gK = kimg + ((size_t)bh * NT + (T)) * 16384 + wid * 4096 +   \
                     lane * 16;                                              \
    char* lK = ldsK[BUF] + wid * 4096;                                       \
    _Pragma("unroll") for (int j = 0; j < 4; ++j)                            \
      gl_lds16(gK + j * 1024, lK + j * 1024); }

#define STAGE_V(T, BUF)                                                      \
  { const char* gV = vimg + ((size_t)bh * NT + (T)) * 16384 + wid * 4096 +   \
                     lane * 16;                                              \
    char* lV = ldsV[BUF] + wid * 4096;                                       \
    _Pragma("unroll") for (int j = 0; j < 4; ++j)                            \
      gl_lds16(gV + j * 1024, lV + j * 1024); }

  // ---- prologue: DMA tile 0 (drains at the loop's first barrier) ----
  STAGE_K(0, 0)
  STAGE_V(0, 0)

  for (int t = 0; t < NT; ++t) {
    __syncthreads();                 // tile t DMA landed; old-buffer reads done
    const int buf = t & 1;
    const char* Kl = ldsK[buf];
    const char* Vl = ldsV[buf];
    const bool more = (t + 1 < NT);

    // mask(t) first (older in vmcnt FIFO than the DMAs below -> softmax's
    // wait leaves the prefetch in flight)
    bf16x2 mreg[16];
    {
      const bf16x2* MTp = mt2_g + (size_t)(t * 32) * SEQ + qrow;
#pragma unroll
      for (int r = 0; r < 16; ++r) {
        const int kl = (r & 3) + 8 * (r >> 2) + 4 * hi;
        mreg[r] = MTp[(size_t)kl * SEQ];
      }
    }

    if (more) {
      STAGE_K(t + 1, buf ^ 1)        // ages across QK + softmax + PV
      STAGE_V(t + 1, buf ^ 1)
    }

    // ---- QK^T: S^T[k][q], two 32x32 tiles, 16 MFMAs ----
    f32x16 s0, s1;
#pragma unroll
    for (int r = 0; r < 16; ++r) { s0[r] = 0.f; s1[r] = 0.f; }
#pragma unroll
    for (int kd = 0; kd < 8; ++kd) {
      int b0 = ql * 256 + kd * 32 + hi * 16; b0 ^= (ql & 7) << 4;
      bf16x8 kf0 = *(const bf16x8*)(Kl + b0);
      bf16x8 kf1 = *(const bf16x8*)(Kl + b0 + 8192);
      s0 = __builtin_amdgcn_mfma_f32_32x32x16_bf16(kf0, qf[kd], s0, 0, 0, 0);
      s1 = __builtin_amdgcn_mfma_f32_32x32x16_bf16(kf1, qf[kd], s1, 0, 0, 0);
    }

    // ---- softmax numerator, no max subtraction, no cross-lane ops ----
    float p0[16], p1[16];
#pragma unroll
    for (int r = 0; r < 16; ++r) {
      p0[r] = __builtin_amdgcn_exp2f(fmaf(s0[r], SCALE_L2E, (float)mreg[r][0]));
      p1[r] = __builtin_amdgcn_exp2f(fmaf(s1[r], SCALE_L2E, (float)mreg[r][1]));
    }
#pragma unroll
    for (int r = 0; r < 16; ++r) lsum[r] += p0[r] + p1[r];

    // ---- P^T B-fragments straight from registers (slot map kappa) ----
    bf16x8 pb[2][2];
#pragma unroll
    for (int kf = 0; kf < 2; ++kf) {
      pb[0][kf] = bf16x8{(bf16_t)p0[8*kf+0], (bf16_t)p0[8*kf+1],
                         (bf16_t)p0[8*kf+2], (bf16_t)p0[8*kf+3],
                         (bf16_t)p0[8*kf+4], (bf16_t)p0[8*kf+5],
                         (bf16_t)p0[8*kf+6], (bf16_t)p0[8*kf+7]};
      pb[1][kf] = bf16x8{(bf16_t)p1[8*kf+0], (bf16_t)p1[8*kf+1],
                         (bf16_t)p1[8*kf+2], (bf16_t)p1[8*kf+3],
                         (bf16_t)p1[8*kf+4], (bf16_t)p1[8*kf+5],
                         (bf16_t)p1[8*kf+6], (bf16_t)p1[8*kf+7]};
    }

    // ---- PV: O^T += V^T · P^T, 16 MFMAs ----
#pragma unroll
    for (int tt = 0; tt < 2; ++tt)
#pragma unroll
      for (int kf = 0; kf < 2; ++kf) {
        const int kg = tt * 2 + kf;
#pragma unroll
        for (int dt = 0; dt < 4; ++dt) {
          const int d = dt * 32 + ql;
          int byt = d * 128 + kg * 32 + hi * 16; byt ^= (d & 7) << 4;
          bf16x8 vf = *(const bf16x8*)(Vl + byt);
          ot[dt] = __builtin_amdgcn_mfma_f32_32x32x16_bf16(vf, pb[tt][kf], ot[dt], 0, 0, 0);
        }
      }
  }

  // ---- epilogue: single l reduction, then O[q][d] = O^T / l ----
  float ls[16];
#pragma unroll
  for (int r = 0; r < 16; ++r) ls[r] = lsum[r];
#pragma unroll
  for (int off = 8; off > 0; off >>= 1)
#pragma unroll
    for (int r = 0; r < off; ++r) ls[r] += ls[r + off];
  const float l_run = ls[0] + __shfl_xor(ls[0], 32, 64);

  const float rinv = 1.f / l_run;
  float* Op = Ob + (size_t)qrow * HD;
#pragma unroll
  for (int dt = 0; dt < 4; ++dt)
#pragma unroll
    for (int r = 0; r < 16; ++r) {
      const int d = dt * 32 + (r & 3) + 8 * (r >> 2) + 4 * hi;
      Op[d] = ot[dt][r] * rinv;
    }
}

// ---------------------------------------------------------------------------
// Fallback: R4 champion (fp32 K/V staging, fp32 transposed mask)
// ---------------------------------------------------------------------------
__global__ __launch_bounds__(256, 2)
void attn_fwd_fb(const float* __restrict__ q_g, const float* __restrict__ k_g,
                 const float* __restrict__ v_g, const float* __restrict__ mt_g,
                 float* __restrict__ o_g) {
  __shared__ __align__(16) char ldsK[2][KVB * 256];
  __shared__ __align__(16) char ldsV[2][HD * 128];

  const int tid  = threadIdx.x;
  const int wid  = tid >> 6;
  const int lane = tid & 63;
  const int hi   = lane >> 5;
  const int ql   = lane & 31;

  const int lin = blockIdx.x;
  const int xcd = lin & 7;
  const int idx = lin >> 3;
  const int bh  = xcd + 8 * (idx >> 4);
  const int q0  = (idx & 15) * 128;

  const float* Qb = q_g + (size_t)bh * SEQ * HD;
  const float* Kb = k_g + (size_t)bh * SEQ * HD;
  const float* Vb = v_g + (size_t)bh * SEQ * HD;
  float*       Ob = o_g + (size_t)bh * SEQ * HD;

  const int qrow = q0 + wid * 32 + ql;

  bf16x8 qf[8];
#pragma unroll
  for (int kd = 0; kd < 8; ++kd) {
    const float* p = Qb + (size_t)qrow * HD + kd * 16 + hi * 8;
    float4 a = *(const float4*)p;
    float4 b = *(const float4*)(p + 4);
    qf[kd] = bf16x8{(bf16_t)a.x, (bf16_t)a.y, (bf16_t)a.z, (bf16_t)a.w,
                    (bf16_t)b.x, (bf16_t)b.y, (bf16_t)b.z, (bf16_t)b.w};
  }

  f32x16 ot[4];
#pragma unroll
  for (int dt = 0; dt < 4; ++dt)
#pragma unroll
    for (int r = 0; r < 16; ++r) ot[dt][r] = 0.f;

  float m_run = -INFINITY, l_run = 0.f;

  float4 kreg[8], vA[4], vB[4];
  const int vp  = tid & 31;
  const int vcb = tid >> 5;
  const int vkb = ((vp >> 3) << 5) +
                  (((vp & 1) | ((vp & 2) << 1) | ((vp & 4) >> 1)) << 2);

#define KF_ISSUE(K0)                                                         \
  { _Pragma("unroll") for (int i = 0; i < 8; ++i) {                          \
      const int ix = tid + i * 256;                                          \
      kreg[i] = *(const float4*)(Kb + (size_t)((K0) + (ix >> 5)) * HD +      \
                                 (ix & 31) * 4); } }

#define KF_WRITE(BUF)                                                        \
  { char* dK = ldsK[BUF];                                                    \
    _Pragma("unroll") for (int i = 0; i < 8; ++i) {                          \
      const int ix = tid + i * 256;                                          \
      const int row = ix >> 5; const int c4 = ix & 31;                       \
      int byt = row * 256 + c4 * 8; byt ^= (row & 7) << 4;                   \
      float4 v = kreg[i];                                                    \
      *(bf16x4*)(dK + byt) =                                                 \
          bf16x4{(bf16_t)v.x, (bf16_t)v.y, (bf16_t)v.z, (bf16_t)v.w}; } }

#define VF_ISSUE_A(K0)                                                       \
  { _Pragma("unroll") for (int i = 0; i < 2; ++i) {                          \
      const int c4 = vcb + 8 * i;                                            \
      vA[2*i]   = *(const float4*)(Vb + (size_t)((K0) + 2*vp)     * HD + c4*4); \
      vA[2*i+1] = *(const float4*)(Vb + (size_t)((K0) + 2*vp + 1) * HD + c4*4); } }

#define VF_ISSUE_B(K0)                                                       \
  { _Pragma("unroll") for (int i = 0; i < 2; ++i) {                          \
      const int c4 = vcb + 16 + 8 * i;                                       \
      vB[2*i]   = *(const float4*)(Vb + (size_t)((K0) + 2*vp)     * HD + c4*4); \
      vB[2*i+1] = *(const float4*)(Vb + (size_t)((K0) + 2*vp + 1) * HD + c4*4); } }

#define VF_WRITE_X(BUF, REGS, COFF)                                          \
  { char* dV = ldsV[BUF];                                                    \
    _Pragma("unroll") for (int i = 0; i < 2; ++i) {                          \
      const int c4 = vcb + (COFF) + 8 * i;                                   \
      const float* r0 = (const float*)&REGS[2*i];                            \
      const float* r1 = (const float*)&REGS[2*i+1];                          \
      _Pragma("unroll") for (int j = 0; j < 4; ++j) {                        \
        const int d = c4 * 4 + j;                                            \
        int byt = d * 128 + vkb; byt ^= (d & 7) << 4;                        \
        *(bf16x2*)(dV + byt) = bf16x2{(bf16_t)r0[j], (bf16_t)r1[j]}; } } }

  KF_ISSUE(0)
  VF_ISSUE_A(0)
  VF_ISSUE_B(0)
  KF_WRITE(0)
  VF_WRITE_X(0, vA, 0)
  VF_WRITE_X(0, vB, 16)

  for (int t = 0; t < NT; ++t) {
    __syncthreads();
    const int buf = t & 1;
    const char* Kl = ldsK[buf];
    const char* Vl = ldsV[buf];
    const bool more = (t + 1 < NT);

    if (more) { KF_ISSUE((t + 1) * KVB) }

    float mk0[16], mk1[16];
    {
      const float* MTp = mt_g + (size_t)(t * KVB) * SEQ + qrow;
#pragma unroll
      for (int r = 0; r < 16; ++r) {
        const int k = (r & 3) + 8 * (r >> 2) + 4 * hi;
        mk0[r] = MTp[(size_t)k * SEQ];
        mk1[r] = MTp[(size_t)(k + 32) * SEQ];
      }
    }

    if (more) { VF_ISSUE_A((t + 1) * KVB) }

    f32x16 s0, s1;
#pragma unroll
    for (int r = 0; r < 16; ++r) { s0[r] = 0.f; s1[r] = 0.f; }
#pragma unroll
    for (int kd = 0; kd < 8; ++kd) {
      int b0 = ql * 256 + kd * 32 + hi * 16; b0 ^= (ql & 7) << 4;
      bf16x8 kf0 = *(const bf16x8*)(Kl + b0);
      bf16x8 kf1 = *(const bf16x8*)(Kl + b0 + 8192);
      s0 = __builtin_amdgcn_mfma_f32_32x32x16_bf16(kf0, qf[kd], s0, 0, 0, 0);
      s1 = __builtin_amdgcn_mfma_f32_32x32x16_bf16(kf1, qf[kd], s1, 0, 0, 0);
    }

    if (more) {
      VF_WRITE_X(buf ^ 1, vA, 0)
      VF_ISSUE_B((t + 1) * KVB)
    }

    float x0[16], x1[16];
#pragma unroll
    for (int r = 0; r < 16; ++r) {
      x0[r] = fmaf(s0[r], SCALE_L2E, mk0[r]);
      x1[r] = fmaf(s1[r], SCALE_L2E, mk1[r]);
    }
    float tm[16];
#pragma unroll
    for (int r = 0; r < 16; ++r) tm[r] = fmaxf(x0[r], x1[r]);
#pragma unroll
    for (int off = 8; off > 0; off >>= 1)
#pragma unroll
      for (int r = 0; r < off; ++r) tm[r] = fmaxf(tm[r], tm[r + off]);
    const float mx   = fmaxf(tm[0], __shfl_xor(tm[0], 32, 64));
    const float mnew = fmaxf(m_run, mx);
    const float fac  = __builtin_amdgcn_exp2f(m_run - mnew);
    m_run = mnew;

    float p0[16], p1[16];
#pragma unroll
    for (int r = 0; r < 16; ++r) {
      p0[r] = __builtin_amdgcn_exp2f(x0[r] - mnew);
      p1[r] = __builtin_amdgcn_exp2f(x1[r] - mnew);
    }
    float ts[16];
#pragma unroll
    for (int r = 0; r < 16; ++r) ts[r] = p0[r] + p1[r];
#pragma unroll
    for (int off = 8; off > 0; off >>= 1)
#pragma unroll
      for (int r = 0; r < off; ++r) ts[r] += ts[r + off];
    const float sum = ts[0] + __shfl_xor(ts[0], 32, 64);
    l_run = l_run * fac + sum;

#pragma unroll
    for (int dt = 0; dt < 4; ++dt)
#pragma unroll
      for (int r = 0; r < 16; ++r) ot[dt][r] *= fac;

    bf16x8 pb[2][2];
#pragma unroll
    for (int kf = 0; kf < 2; ++kf) {
      pb[0][kf] = bf16x8{(bf16_t)p0[8*kf+0], (bf16_t)p0[8*kf+1],
                         (bf16_t)p0[8*kf+2], (bf16_t)p0[8*kf+3],
                         (bf16_t)p0[8*kf+4], (bf16_t)p0[8*kf+5],
                         (bf16_t)p0[8*kf+6], (bf16_t)p0[8*kf+7]};
      pb[1][kf] = bf16x8{(bf16_t)p1[8*kf+0], (bf16_t)p1[8*kf+1],
                         (bf16_t)p1[8*kf+2], (bf16_t)p1[8*kf+3],
                         (bf16_t)p1[8*kf+4], (bf16_t)p1[8*kf+5],
                         (bf16_t)p1[8*kf+6], (bf16_t)p1[8*kf+7]};
    }

#pragma unroll
    for (int tt = 0; tt < 2; ++tt)
#pragma unroll
      for (int kf = 0; kf < 2; ++kf) {
        const int kg = tt * 2 + kf;
#pragma unroll
        for (int dt = 0; dt < 4; ++dt) {
          const int d = dt * 32 + ql;
          int byt = d * 128 + kg * 32 + hi * 16; byt ^= (d & 7) << 4;
          bf16x8 vf = *(const bf16x8*)(Vl + byt);
          ot[dt] = __builtin_amdgcn_mfma_f32_32x32x16_bf16(vf, pb[tt][kf], ot[dt], 0, 0, 0);
        }
      }

    if (more) {
      VF_WRITE_X(buf ^ 1, vB, 16)
      KF_WRITE(buf ^ 1)
    }
  }

  const float rinv = 1.f / l_run;
  float* Op = Ob + (size_t)qrow * HD;
#pragma unroll
  for (int dt = 0; dt < 4; ++dt)
#pragma unroll
    for (int r = 0; r < 16; ++r) {
      const int d = dt * 32 + (r & 3) + 8 * (r >> 2) + 4 * hi;
      Op[d] = ot[dt][r] * rinv;
    }
}

extern "C" void kernel_launch(void* const* d_in, const int* in_sizes, int n_in,
                              void* d_out, int out_size, void* d_ws, size_t ws_size,
                              hipStream_t stream) {
  (void)in_sizes; (void)n_in; (void)out_size;
  const float* Q = (const float*)d_in[0];
  const float* K = (const float*)d_in[1];
  const float* V = (const float*)d_in[2];
  const float* M = (const float*)d_in[3];
  float*       O = (float*)d_out;

  const size_t szImg = (size_t)64 * NT * 16384;            // 33.55 MB per image
  const size_t szM2  = (size_t)(SEQ / KVB) * 32 * SEQ * 4; // 8.39 MB

  if (ws_size >= 2 * szImg + szM2) {
    char*   KI  = (char*)d_ws;
    char*   VI  = (char*)d_ws + szImg;
    bf16x2* MT2 = (bf16x2*)((char*)d_ws + 2 * szImg);
    mk_kimg<<<64 * NT, 256, 0, stream>>>(K, KI);
    mk_vimg<<<64 * NT, 256, 0, stream>>>(V, VI);
    mask_tr2<<<dim3(SEQ / 64, SEQ / 32), 256, 0, stream>>>(M, MT2);
    attn_fwd_v8<<<dim3(1024), 256, 0, stream>>>(Q, KI, VI, MT2, O);
  } else {
    float* MT = (float*)d_ws;   // 16.8 MB (proven available)
    mask_tr<<<dim3(SEQ / 32, SEQ / 32), 256, 0, stream>>>(M, MT);
    attn_fwd_fb<<<dim3(1024), 256, 0, stream>>>(Q, K, V, MT, O);
  }
}